// Round 13
// baseline (361.145 us; speedup 1.0000x reference)
//
#include <hip/hip_runtime.h>

#define NB 4
#define NN 200000
#define HH 512
#define WW 512
#define CC 64
#define PP 150000
#define RP 100000
#define HWSZ (HH * WW)
#define NPTS (NB * NN)
#define XSHIFT 4                           // 16 floats = one 64B line along x
#define BINS_PER_B (HH * (WW >> XSHIFT))   // 16384
#define NBINS (NB * BINS_PER_B)            // 65536

// wbuf layout (32-bit words):
#define WB_WCAT 0
#define WB_WTAIL 5120
#define WB_BCAT 5312
#define WB_BFRAG 5376
#define WB_BFRAG2 (WB_BFRAG + 3072)
#define WBUF_WORDS (WB_BFRAG2 + 256)       // 8704

typedef _Float16 half8_t __attribute__((ext_vector_type(8)));
typedef _Float16 half2_t __attribute__((ext_vector_type(2)));
typedef float f32x4 __attribute__((ext_vector_type(4)));

__device__ __forceinline__ unsigned packh(float a, float b) {
    half2_t h; h.x = (_Float16)a; h.y = (_Float16)b;
    unsigned u; __builtin_memcpy(&u, &h, 4); return u;
}
__device__ __forceinline__ float gelu(float v) {
    return 0.5f * v * (1.0f + erff(v * 0.70710678118654752f));
}
__device__ __forceinline__ int bin_of(int b, int y, int x) {
    return b * BINS_PER_B + y * (WW >> XSHIFT) + (x >> XSHIFT);
}

// ---------------- prep1: zero bins + collapsed weights (grid 64) ----------------

__global__ __launch_bounds__(256) void prep1(
    const float* __restrict__ Wf, const float* __restrict__ bf,
    const float* __restrict__ Wp, const float* __restrict__ bp,
    const float* __restrict__ W1, const float* __restrict__ b1,
    float* __restrict__ wbuf, unsigned* __restrict__ cnt)
{
    int g = blockIdx.x * 256 + threadIdx.x;      // 0..16383
    uint4 z4 = {0u, 0u, 0u, 0u};
    ((uint4*)cnt)[g] = z4;                        // 16384*4 = 65536 bins

    if (g < 5120) {                               // Wcat
        int r = g >> 5, j = g & 31;
        float s = 0.f;
        if (r < 64) {
            for (int k = 0; k < 32; ++k) s += Wf[r * 32 + k] * W1[k * 32 + j];
        } else {
            int rr = r - 64;
            for (int k = 0; k < 32; ++k) s += Wp[rr * 32 + k] * W1[(32 + k) * 32 + j];
        }
        wbuf[WB_WCAT + g] = s;
    } else if (g < 5312) {                        // Wtail
        int idx = g - 5120;
        int r = idx >> 5, j = idx & 31;
        float s = 0.f;
        for (int k = 0; k < 32; ++k) s += Wf[(64 + r) * 32 + k] * W1[k * 32 + j];
        wbuf[WB_WTAIL + idx] = s;
    } else if (g < 5344) {                        // bcat
        int j = g - 5312;
        float s = b1[j];
        for (int k = 0; k < 32; ++k)
            s += bf[k] * W1[k * 32 + j] + bp[k] * W1[(32 + k) * 32 + j];
        wbuf[WB_BCAT + j] = s;
    }
}

// ---------------- hist (+ yx cache) ----------------

__global__ __launch_bounds__(256) void hist_kernel(
    const int* __restrict__ voxel, unsigned* __restrict__ cnt,
    unsigned* __restrict__ yxp) {
    int pid = blockIdx.x * 256 + threadIdx.x;
    if (pid >= NPTS) return;
    int b = pid / NN;
    int y = voxel[(size_t)pid * 3 + 1];
    int x = voxel[(size_t)pid * 3 + 2];
    yxp[pid] = ((unsigned)y << 16) | (unsigned)x;
    atomicAdd(&cnt[bin_of(b, y, x)], 1u);
}

// ---------------- scan (single block) + BF fragment build tail ----------------

__device__ __forceinline__ float wrowf(const float* __restrict__ wbuf, int k, int col) {
    if (k < 160) return wbuf[WB_WCAT + k * 32 + col];
    if (k < 166) return wbuf[WB_WTAIL + (k - 160) * 32 + col];
    if (k == 166) return wbuf[WB_BCAT + col];
    return 0.f;
}

__global__ __launch_bounds__(1024) void scan_kernel(
    const unsigned* __restrict__ cnt, unsigned* __restrict__ off,
    const float* __restrict__ wbufc, float* __restrict__ wbuf,
    const float* __restrict__ W2) {
    __shared__ unsigned lds[1024];
    int t = threadIdx.x;
    const uint4* c4 = (const uint4*)cnt;
    unsigned sum = 0;
    #pragma unroll 4
    for (int i = 0; i < 16; ++i) {
        uint4 c = c4[t * 16 + i];
        sum += c.x + c.y + c.z + c.w;
    }
    lds[t] = sum;
    __syncthreads();
    for (int d = 1; d < 1024; d <<= 1) {
        unsigned v = (t >= d) ? lds[t - d] : 0u;
        __syncthreads();
        lds[t] += v;
        __syncthreads();
    }
    unsigned run = (t == 0) ? 0u : lds[t - 1];
    uint4* o4 = (uint4*)off;
    #pragma unroll 4
    for (int i = 0; i < 16; ++i) {
        uint4 c = c4[t * 16 + i];
        uint4 o;
        o.x = run;
        o.y = o.x + c.x;
        o.z = o.y + c.y;
        o.w = o.z + c.z;
        run = o.w + c.w;
        o4[t * 16 + i] = o;
    }
    // BF fragment build (independent of scan data; wbufc written by prep1)
    unsigned* BF = (unsigned*)(wbuf + WB_BFRAG);
    for (int idx = t; idx < 3072 + 256; idx += 1024) {
        if (idx < 3072) {
            int w = idx & 3;
            int slot = idx >> 2;
            int l = slot & 63;
            int rest = slot >> 6;
            int tt = rest % 6, nt = rest / 6;
            int k = tt * 32 + (l >> 4) * 8 + w * 2;
            int col = nt * 16 + (l & 15);
            BF[idx] = packh(wrowf(wbufc, k, col), wrowf(wbufc, k + 1, col));
        } else {
            int i2 = idx - 3072;
            int w = i2 & 3, l = i2 >> 2;
            int k2 = (l >> 4) * 8 + w * 2, col = l & 15;
            BF[i2 + 3072] = packh(W2[k2 * 16 + col], W2[(k2 + 1) * 16 + col]);
        }
    }
}

// ---------------- scatter: write fused {pid, yx} ----------------

__global__ __launch_bounds__(256) void scatter_kernel(
    const unsigned* __restrict__ yxp, unsigned* __restrict__ off,
    uint2* __restrict__ oy) {
    int pid = blockIdx.x * 256 + threadIdx.x;
    if (pid >= NPTS) return;
    unsigned p = yxp[pid];
    int y = (int)(p >> 16), x = (int)(p & 0xffffu);
    unsigned pos = atomicAdd(&off[bin_of(pid / NN, y, x)], 1u);
    uint2 q; q.x = (unsigned)pid; q.y = p;
    oy[pos] = q;
}

// ---------------- phase G: plane-major gather -> f16 A-fragments ----------------
// grid (n/256, 16). blockIdx.y = channel-octet; x-major dispatch sweeps each
// octet across the full sorted point range (the 5.7 TB/s regime, R3-proven).
// Writes frag[(tile*4 + tslice)*64 + hi*16 + lo] = point lo's 8 channels.

__global__ __launch_bounds__(256) void gather_frag(
    const float* __restrict__ pc0_map, const float* __restrict__ flow_map,
    const uint2* __restrict__ oy,
    uint4* __restrict__ frag, int base, int n)
{
    int t = blockIdx.x * 256 + threadIdx.x;
    if (t >= n) return;
    int o = blockIdx.y;                      // 0..7 flow octets, 8..15 pc octets
    uint2 q = oy[base + t];
    int pid = (int)q.x;
    int y = (int)(q.y >> 16), x = (int)(q.y & 0xffffu);
    int b = pid / NN;
    const float* m = (o < 8) ? flow_map : pc0_map;
    int ch0 = ((o >> 2) & 1) * 32 + (o & 3) * 8;
    const float* mb = m + ((size_t)(b * CC + ch0)) * HWSZ + (size_t)y * WW + x;
    float u[8];
    #pragma unroll
    for (int j = 0; j < 8; ++j) u[j] = mb[(size_t)j * HWSZ];
    uint4 fr;
    fr.x = packh(u[0], u[1]);
    fr.y = packh(u[2], u[3]);
    fr.z = packh(u[4], u[5]);
    fr.w = packh(u[6], u[7]);
    int tl = t >> 4;                         // tile within chunk
    int tslice = o >> 2;                     // 0..3 (A-slice)
    frag[((size_t)(tl * 4 + tslice)) * 64 + (o & 3) * 16 + (t & 15)] = fr;
}

// ---------------- phase M: dense-fragment MFMA MLP ----------------

__global__ __launch_bounds__(512, 8) void mlp_fused2(
    const uint4* __restrict__ frag,
    const float* __restrict__ pc0_fea, const float* __restrict__ flows,
    const float* __restrict__ pose_flows, const float* __restrict__ radar_pose,
    const int* __restrict__ point_idxes,
    const uint2* __restrict__ oy,
    const float* __restrict__ wbuf,
    const float* __restrict__ b2, const float* __restrict__ W3,
    const float* __restrict__ b3,
    int base,
    float* __restrict__ out)
{
    __shared__ uint4 Bf[832];
    __shared__ __align__(16) _Float16 zl[8][16 * 48];
    {
        const uint4* wsrc = (const uint4*)(wbuf + WB_BFRAG);
        for (int i = threadIdx.x; i < 832; i += 512) Bf[i] = wsrc[i];
    }
    __syncthreads();

    int w = threadIdx.x >> 6;
    int lane = threadIdx.x & 63;
    int lo = lane & 15, hi = lane >> 4;
    int tlc = blockIdx.x * 8 + w;            // tile within chunk
    int s0 = base + tlc * 16;

    uint2 q = oy[s0 + lo];
    int pid = (int)q.x;
    int b = pid / NN;

    half8_t A[6];
    // map slices from frag: fully coalesced 16B/lane
    #pragma unroll
    for (int t = 0; t < 4; ++t) {
        uint4 fr = frag[((size_t)(tlc * 4 + t)) * 64 + lane];
        __builtin_memcpy(&A[t], &fr, 16);
    }
    {
        const f32x4* fe4 = (const f32x4*)(pc0_fea + (size_t)pid * 32 + hi * 8);
        f32x4 fa = fe4[0];
        f32x4 fb = fe4[1];
        A[4][0] = (_Float16)fa.x; A[4][1] = (_Float16)fa.y;
        A[4][2] = (_Float16)fa.z; A[4][3] = (_Float16)fa.w;
        A[4][4] = (_Float16)fb.x; A[4][5] = (_Float16)fb.y;
        A[4][6] = (_Float16)fb.z; A[4][7] = (_Float16)fb.w;
    }
    {
        half8_t a5;
        #pragma unroll
        for (int j = 0; j < 8; ++j) a5[j] = (_Float16)0.f;
        if (hi == 0) {
            const float* fl = flows + (size_t)pid * 3;
            int pi = point_idxes[pid];
            const float* ps = (pi < PP) ? (pose_flows + ((size_t)b * PP + pi) * 3)
                                        : (radar_pose + ((size_t)b * RP + (pi - PP)) * 3);
            a5[0] = (_Float16)fl[0]; a5[1] = (_Float16)fl[1]; a5[2] = (_Float16)fl[2];
            a5[3] = (_Float16)ps[0]; a5[4] = (_Float16)ps[1]; a5[5] = (_Float16)ps[2];
            a5[6] = (_Float16)1.0f;
        }
        A[5] = a5;
    }

    // layer1 (collapsed): z[16 pts][32 ch]
    f32x4 acc0 = {0.f, 0.f, 0.f, 0.f};
    f32x4 acc1 = {0.f, 0.f, 0.f, 0.f};
    #pragma unroll
    for (int t = 0; t < 6; ++t) {
        half8_t B0, B1;
        uint4 u0 = Bf[t * 64 + lane];
        uint4 u1 = Bf[(6 + t) * 64 + lane];
        __builtin_memcpy(&B0, &u0, 16);
        __builtin_memcpy(&B1, &u1, 16);
        acc0 = __builtin_amdgcn_mfma_f32_16x16x32_f16(A[t], B0, acc0, 0, 0, 0);
        acc1 = __builtin_amdgcn_mfma_f32_16x16x32_f16(A[t], B1, acc1, 0, 0, 0);
    }

    // gelu -> z LDS (f16), C-layout: point = hi*4+r, ch = nt*16+lo
    _Float16* zw = zl[w];
    #pragma unroll
    for (int r = 0; r < 4; ++r) {
        zw[(hi * 4 + r) * 48 + lo]      = (_Float16)gelu(acc0[r]);
        zw[(hi * 4 + r) * 48 + 16 + lo] = (_Float16)gelu(acc1[r]);
    }

    // layer2
    half8_t A2, B2;
    __builtin_memcpy(&A2, &zw[lo * 48 + hi * 8], 16);
    {
        uint4 u2 = Bf[768 + lane];
        __builtin_memcpy(&B2, &u2, 16);
    }
    f32x4 zz4 = {0.f, 0.f, 0.f, 0.f};
    f32x4 acc2 = __builtin_amdgcn_mfma_f32_16x16x32_f16(A2, B2, zz4, 0, 0, 0);

    // epilogue
    float b2v = b2[lo];
    float w3v = W3[lo];
    float e0 = gelu(acc2[0] + b2v) * w3v;
    float e1 = gelu(acc2[1] + b2v) * w3v;
    float e2 = gelu(acc2[2] + b2v) * w3v;
    float e3 = gelu(acc2[3] + b2v) * w3v;
    #pragma unroll
    for (int m = 1; m <= 8; m <<= 1) {
        e0 += __shfl_xor(e0, m);
        e1 += __shfl_xor(e1, m);
        e2 += __shfl_xor(e2, m);
        e3 += __shfl_xor(e3, m);
    }
    int p2 = hi * 4 + lo;
    int pid2 = __shfl(pid, p2 & 15);
    if (lo < 4) {
        float zs = (lo == 0 ? e0 : lo == 1 ? e1 : lo == 2 ? e2 : e3) + b3[0];
        float score = 1.0f / (1.0f + expf(-zs));
        out[(size_t)NPTS + pid2] = score;
        out[pid2] = (score > 0.5f) ? 1.0f : 0.0f;
    }
}

extern "C" void kernel_launch(void* const* d_in, const int* in_sizes, int n_in,
                              void* d_out, int out_size, void* d_ws, size_t ws_size,
                              hipStream_t stream) {
    const float* pc0_map    = (const float*)d_in[0];
    const float* flow_map   = (const float*)d_in[1];
    const float* pc0_fea    = (const float*)d_in[2];
    const float* flows      = (const float*)d_in[3];
    const float* pose_flows = (const float*)d_in[4];
    const float* radar_pose = (const float*)d_in[5];
    const int*   voxel      = (const int*)d_in[6];
    const int*   pidx       = (const int*)d_in[7];
    const float* W_flow = (const float*)d_in[8];
    const float* b_flow = (const float*)d_in[9];
    const float* W_pc   = (const float*)d_in[10];
    const float* b_pc   = (const float*)d_in[11];
    const float* W1     = (const float*)d_in[12];
    const float* b1     = (const float*)d_in[13];
    const float* W2     = (const float*)d_in[14];
    const float* b2     = (const float*)d_in[15];
    const float* W3     = (const float*)d_in[16];
    const float* b3     = (const float*)d_in[17];

    // ws: cnt[NBINS] | off[NBINS] | oy[NPTS] (uint2) | yxp[NPTS] | wbuf | frag[]
    size_t fixed_need = (size_t)(2 * NBINS + 3 * NPTS) * sizeof(unsigned)
                      + (size_t)WBUF_WORDS * sizeof(float);
    if (ws_size < fixed_need + (size_t)256 * 256) return;
    unsigned* cnt = (unsigned*)d_ws;
    unsigned* off = cnt + NBINS;
    uint2* oy = (uint2*)(off + NBINS);
    unsigned* yxp = (unsigned*)(oy + NPTS);
    float* wbuf = (float*)(yxp + NPTS);
    uint4* frag = (uint4*)(wbuf + WBUF_WORDS);

    int ptBlocks = NPTS / 256;               // 3125 exact

    hipLaunchKernelGGL(prep1, dim3(64), dim3(256), 0, stream,
                       W_flow, b_flow, W_pc, b_pc, W1, b1, wbuf, cnt);
    hipLaunchKernelGGL(hist_kernel, dim3(ptBlocks), dim3(256), 0, stream,
                       voxel, cnt, yxp);
    hipLaunchKernelGGL(scan_kernel, dim3(1), dim3(1024), 0, stream,
                       cnt, off, wbuf, wbuf, W2);
    hipLaunchKernelGGL(scatter_kernel, dim3(ptBlocks), dim3(256), 0, stream,
                       yxp, off, oy);

    // chunk size: 256 B of frag per point, multiple of 256 points
    size_t avail = ws_size - fixed_need;
    long long cp = (long long)(avail / 256);
    if (cp > NPTS) cp = NPTS;
    int CP = (int)(cp & ~255LL);
    if (CP < 256) return;

    for (int basePt = 0; basePt < NPTS; basePt += CP) {
        int n = NPTS - basePt;
        if (n > CP) n = CP;                 // n is a multiple of 256
        dim3 gG(n / 256, 16);
        hipLaunchKernelGGL(gather_frag, gG, dim3(256), 0, stream,
                           pc0_map, flow_map, oy, frag, basePt, n);
        hipLaunchKernelGGL(mlp_fused2, dim3(n / 128), dim3(512), 0, stream,
                           frag, pc0_fea, flows, pose_flows, radar_pose,
                           pidx, oy, wbuf, b2, W3, b3, basePt, (float*)d_out);
    }
}

// Round 14
// 194.270 us; speedup vs baseline: 1.8590x; 1.8590x over previous
//
#include <hip/hip_runtime.h>

#define NB 4
#define NN 200000
#define HH 512
#define WW 512
#define CC 64
#define PP 150000
#define RP 100000
#define HWSZ (HH * WW)                     // 262144 = 2^18
#define NPTS (NB * NN)
#define NPIX (NB * HWSZ)                   // 1048576

// wbuf layout (32-bit words):
#define WB_WCAT 0
#define WB_WTAIL 5120
#define WB_BCAT 5312
#define WB_BFRAG 5376
#define WB_BFRAG2 (WB_BFRAG + 3072)
#define WBUF_WORDS (WB_BFRAG2 + 256)       // 8704

typedef _Float16 half8_t __attribute__((ext_vector_type(8)));
typedef _Float16 half2_t __attribute__((ext_vector_type(2)));
typedef float f32x4 __attribute__((ext_vector_type(4)));

__device__ __forceinline__ unsigned packh(float a, float b) {
    half2_t h; h.x = (_Float16)a; h.y = (_Float16)b;
    unsigned u; __builtin_memcpy(&u, &h, 4); return u;
}
__device__ __forceinline__ float gelu(float v) {
    return 0.5f * v * (1.0f + erff(v * 0.70710678118654752f));
}

// ---------------- prep1: collapsed weights (grid 21) ----------------

__global__ __launch_bounds__(256) void prep1(
    const float* __restrict__ Wf, const float* __restrict__ bf,
    const float* __restrict__ Wp, const float* __restrict__ bp,
    const float* __restrict__ W1, const float* __restrict__ b1,
    float* __restrict__ wbuf)
{
    int g = blockIdx.x * 256 + threadIdx.x;

    if (g < 5120) {                               // Wcat
        int r = g >> 5, j = g & 31;
        float s = 0.f;
        if (r < 64) {
            for (int k = 0; k < 32; ++k) s += Wf[r * 32 + k] * W1[k * 32 + j];
        } else {
            int rr = r - 64;
            for (int k = 0; k < 32; ++k) s += Wp[rr * 32 + k] * W1[(32 + k) * 32 + j];
        }
        wbuf[WB_WCAT + g] = s;
    } else if (g < 5312) {                        // Wtail
        int idx = g - 5120;
        int r = idx >> 5, j = idx & 31;
        float s = 0.f;
        for (int k = 0; k < 32; ++k) s += Wf[(64 + r) * 32 + k] * W1[k * 32 + j];
        wbuf[WB_WTAIL + idx] = s;
    } else if (g < 5344) {                        // bcat
        int j = g - 5312;
        float s = b1[j];
        for (int k = 0; k < 32; ++k)
            s += bf[k] * W1[k * 32 + j] + bp[k] * W1[(32 + k) * 32 + j];
        wbuf[WB_BCAT + j] = s;
    }
}

// ---------------- prep2: B-fragment build (1 block 1024) ----------------

__device__ __forceinline__ float wrowf(const float* __restrict__ wbuf, int k, int col) {
    if (k < 160) return wbuf[WB_WCAT + k * 32 + col];
    if (k < 166) return wbuf[WB_WTAIL + (k - 160) * 32 + col];
    if (k == 166) return wbuf[WB_BCAT + col];
    return 0.f;
}

__global__ __launch_bounds__(1024) void prep2(
    const float* __restrict__ wbufc, float* __restrict__ wbuf,
    const float* __restrict__ W2)
{
    int t = threadIdx.x;
    unsigned* BF = (unsigned*)(wbuf + WB_BFRAG);
    for (int idx = t; idx < 3072 + 256; idx += 1024) {
        if (idx < 3072) {
            int w = idx & 3;
            int slot = idx >> 2;
            int l = slot & 63;
            int rest = slot >> 6;
            int tt = rest % 6, nt = rest / 6;
            int k = tt * 32 + (l >> 4) * 8 + w * 2;
            int col = nt * 16 + (l & 15);
            BF[idx] = packh(wrowf(wbufc, k, col), wrowf(wbufc, k + 1, col));
        } else {
            int i2 = idx - 3072;
            int w = i2 & 3, l = i2 >> 2;
            int k2 = (l >> 4) * 8 + w * 2, col = l & 15;
            BF[i2 + 3072] = packh(W2[k2 * 16 + col], W2[(k2 + 1) * 16 + col]);
        }
    }
}

// ---------------- dense 1x1 conv: z_map[pix][32] = maps . Wcat ----------------
// Block 256 = 4 waves = 64 consecutive pixels. Every fetched line fully used.

__global__ __launch_bounds__(256) void conv_map(
    const float* __restrict__ pc0_map, const float* __restrict__ flow_map,
    const float* __restrict__ wbuf, _Float16* __restrict__ zmap)
{
    __shared__ uint4 Bf[832];
    __shared__ __align__(16) _Float16 zl[4][16 * 48];
    {
        const uint4* wsrc = (const uint4*)(wbuf + WB_BFRAG);
        for (int i = threadIdx.x; i < 832; i += 256) Bf[i] = wsrc[i];
    }
    __syncthreads();

    int wv = threadIdx.x >> 6;
    int lane = threadIdx.x & 63;
    int lo = lane & 15, hi = lane >> 4;
    size_t p = (size_t)blockIdx.x * 64 + wv * 16 + lo;   // pixel id
    int b = (int)(p >> 18);                               // HWSZ = 2^18
    size_t inb = p & (size_t)(HWSZ - 1);

    const float* fm = flow_map + (size_t)b * CC * HWSZ + inb;
    const float* pm = pc0_map  + (size_t)b * CC * HWSZ + inb;

    half8_t A[4];
    #pragma unroll
    for (int t = 0; t < 4; ++t) {
        const float* mp = (t < 2) ? fm : pm;
        int ch0 = (t & 1) * 32 + hi * 8;
        float v[8];
        #pragma unroll
        for (int j = 0; j < 8; ++j) v[j] = mp[(size_t)(ch0 + j) * HWSZ];
        #pragma unroll
        for (int j = 0; j < 8; ++j) A[t][j] = (_Float16)v[j];
    }

    f32x4 acc0 = {0.f, 0.f, 0.f, 0.f};
    f32x4 acc1 = {0.f, 0.f, 0.f, 0.f};
    #pragma unroll
    for (int t = 0; t < 4; ++t) {
        half8_t B0, B1;
        uint4 u0 = Bf[t * 64 + lane];
        uint4 u1 = Bf[(6 + t) * 64 + lane];
        __builtin_memcpy(&B0, &u0, 16);
        __builtin_memcpy(&B1, &u1, 16);
        acc0 = __builtin_amdgcn_mfma_f32_16x16x32_f16(A[t], B0, acc0, 0, 0, 0);
        acc1 = __builtin_amdgcn_mfma_f32_16x16x32_f16(A[t], B1, acc1, 0, 0, 0);
    }

    // bounce C-layout -> pixel-major via per-wave LDS, then 16B coalesced write
    _Float16* zw = zl[wv];
    #pragma unroll
    for (int r = 0; r < 4; ++r) {
        zw[(hi * 4 + r) * 48 + lo]      = (_Float16)acc0[r];
        zw[(hi * 4 + r) * 48 + 16 + lo] = (_Float16)acc1[r];
    }
    // lane (lo,hi) writes pixel (block,wv,lo) channels hi*8..hi*8+7
    size_t plo = (size_t)blockIdx.x * 64 + wv * 16 + lo;
    uint4 ov;
    __builtin_memcpy(&ov, &zw[lo * 48 + hi * 8], 16);
    *(uint4*)&zmap[plo * 32 + hi * 8] = ov;
}

// ---------------- point phase: z = z_map + fea.W + tail.W, MLP tail ----------

__global__ __launch_bounds__(512, 8) void point_mlp(
    const _Float16* __restrict__ zmap,
    const float* __restrict__ pc0_fea, const float* __restrict__ flows,
    const float* __restrict__ pose_flows, const float* __restrict__ radar_pose,
    const int* __restrict__ point_idxes, const int* __restrict__ voxel,
    const float* __restrict__ wbuf,
    const float* __restrict__ b2, const float* __restrict__ W3,
    const float* __restrict__ b3,
    float* __restrict__ out)
{
    __shared__ uint4 Bf[832];
    __shared__ __align__(16) _Float16 zl[8][16 * 48];
    {
        const uint4* wsrc = (const uint4*)(wbuf + WB_BFRAG);
        for (int i = threadIdx.x; i < 832; i += 512) Bf[i] = wsrc[i];
    }
    __syncthreads();

    int wv = threadIdx.x >> 6;
    int lane = threadIdx.x & 63;
    int lo = lane & 15, hi = lane >> 4;
    int pid0 = (blockIdx.x * 8 + wv) * 16;       // tiles never straddle batches
    int pid = pid0 + lo;
    int b = pid0 / NN;

    // A4: fea slice (coalesced streaming: consecutive pids)
    half8_t A4;
    {
        const f32x4* fe4 = (const f32x4*)(pc0_fea + (size_t)pid * 32 + hi * 8);
        f32x4 fa = fe4[0];
        f32x4 fb = fe4[1];
        A4[0] = (_Float16)fa.x; A4[1] = (_Float16)fa.y;
        A4[2] = (_Float16)fa.z; A4[3] = (_Float16)fa.w;
        A4[4] = (_Float16)fb.x; A4[5] = (_Float16)fb.y;
        A4[6] = (_Float16)fb.z; A4[7] = (_Float16)fb.w;
    }
    // A5: tail (flows3, pose3, bias-one)
    half8_t A5;
    {
        #pragma unroll
        for (int j = 0; j < 8; ++j) A5[j] = (_Float16)0.f;
        if (hi == 0) {
            const float* fl = flows + (size_t)pid * 3;
            int pi = point_idxes[pid];
            const float* ps = (pi < PP) ? (pose_flows + ((size_t)b * PP + pi) * 3)
                                        : (radar_pose + ((size_t)b * RP + (pi - PP)) * 3);
            A5[0] = (_Float16)fl[0]; A5[1] = (_Float16)fl[1]; A5[2] = (_Float16)fl[2];
            A5[3] = (_Float16)ps[0]; A5[4] = (_Float16)ps[1]; A5[5] = (_Float16)ps[2];
            A5[6] = (_Float16)1.0f;
        }
    }
    // A6: z_map row (64B per point, L3-resident)
    half8_t A6;
    {
        int y = voxel[(size_t)pid * 3 + 1];
        int x = voxel[(size_t)pid * 3 + 2];
        size_t pix = ((size_t)b << 18) + (size_t)y * WW + x;
        uint4 zr = *(const uint4*)&zmap[pix * 32 + hi * 8];
        __builtin_memcpy(&A6, &zr, 16);
    }
    // identity B-fragments for the z_map addend (exact in f16)
    half8_t B60, B61;
    {
        unsigned w0[4], w1[4];
        #pragma unroll
        for (int w = 0; w < 4; ++w) {
            int k0 = hi * 8 + 2 * w, k1 = k0 + 1;
            unsigned a = 0, bmask = 0;
            if (k0 == lo) a |= 0x3C00u;
            if (k1 == lo) a |= 0x3C000000u;
            if (k0 == lo + 16) bmask |= 0x3C00u;
            if (k1 == lo + 16) bmask |= 0x3C000000u;
            w0[w] = a; w1[w] = bmask;
        }
        __builtin_memcpy(&B60, w0, 16);
        __builtin_memcpy(&B61, w1, 16);
    }

    f32x4 acc0 = {0.f, 0.f, 0.f, 0.f};
    f32x4 acc1 = {0.f, 0.f, 0.f, 0.f};
    acc0 = __builtin_amdgcn_mfma_f32_16x16x32_f16(A6, B60, acc0, 0, 0, 0);
    acc1 = __builtin_amdgcn_mfma_f32_16x16x32_f16(A6, B61, acc1, 0, 0, 0);
    {
        half8_t B0, B1;
        uint4 u0 = Bf[4 * 64 + lane];
        uint4 u1 = Bf[(6 + 4) * 64 + lane];
        __builtin_memcpy(&B0, &u0, 16);
        __builtin_memcpy(&B1, &u1, 16);
        acc0 = __builtin_amdgcn_mfma_f32_16x16x32_f16(A4, B0, acc0, 0, 0, 0);
        acc1 = __builtin_amdgcn_mfma_f32_16x16x32_f16(A4, B1, acc1, 0, 0, 0);
        uint4 u2 = Bf[5 * 64 + lane];
        uint4 u3 = Bf[(6 + 5) * 64 + lane];
        __builtin_memcpy(&B0, &u2, 16);
        __builtin_memcpy(&B1, &u3, 16);
        acc0 = __builtin_amdgcn_mfma_f32_16x16x32_f16(A5, B0, acc0, 0, 0, 0);
        acc1 = __builtin_amdgcn_mfma_f32_16x16x32_f16(A5, B1, acc1, 0, 0, 0);
    }

    // gelu -> z LDS (f16)
    _Float16* zw = zl[wv];
    #pragma unroll
    for (int r = 0; r < 4; ++r) {
        zw[(hi * 4 + r) * 48 + lo]      = (_Float16)gelu(acc0[r]);
        zw[(hi * 4 + r) * 48 + 16 + lo] = (_Float16)gelu(acc1[r]);
    }

    // layer2
    half8_t A2, B2;
    __builtin_memcpy(&A2, &zw[lo * 48 + hi * 8], 16);
    {
        uint4 u2 = Bf[768 + lane];
        __builtin_memcpy(&B2, &u2, 16);
    }
    f32x4 zz4 = {0.f, 0.f, 0.f, 0.f};
    f32x4 acc2 = __builtin_amdgcn_mfma_f32_16x16x32_f16(A2, B2, zz4, 0, 0, 0);

    // epilogue
    float b2v = b2[lo];
    float w3v = W3[lo];
    float e0 = gelu(acc2[0] + b2v) * w3v;
    float e1 = gelu(acc2[1] + b2v) * w3v;
    float e2 = gelu(acc2[2] + b2v) * w3v;
    float e3 = gelu(acc2[3] + b2v) * w3v;
    #pragma unroll
    for (int m = 1; m <= 8; m <<= 1) {
        e0 += __shfl_xor(e0, m);
        e1 += __shfl_xor(e1, m);
        e2 += __shfl_xor(e2, m);
        e3 += __shfl_xor(e3, m);
    }
    int p2 = hi * 4 + lo;
    if (lo < 4) {
        float zs = (lo == 0 ? e0 : lo == 1 ? e1 : lo == 2 ? e2 : e3) + b3[0];
        float score = 1.0f / (1.0f + expf(-zs));
        int pid2 = pid0 + p2;
        out[(size_t)NPTS + pid2] = score;
        out[pid2] = (score > 0.5f) ? 1.0f : 0.0f;
    }
}

extern "C" void kernel_launch(void* const* d_in, const int* in_sizes, int n_in,
                              void* d_out, int out_size, void* d_ws, size_t ws_size,
                              hipStream_t stream) {
    const float* pc0_map    = (const float*)d_in[0];
    const float* flow_map   = (const float*)d_in[1];
    const float* pc0_fea    = (const float*)d_in[2];
    const float* flows      = (const float*)d_in[3];
    const float* pose_flows = (const float*)d_in[4];
    const float* radar_pose = (const float*)d_in[5];
    const int*   voxel      = (const int*)d_in[6];
    const int*   pidx       = (const int*)d_in[7];
    const float* W_flow = (const float*)d_in[8];
    const float* b_flow = (const float*)d_in[9];
    const float* W_pc   = (const float*)d_in[10];
    const float* b_pc   = (const float*)d_in[11];
    const float* W1     = (const float*)d_in[12];
    const float* b1     = (const float*)d_in[13];
    const float* W2     = (const float*)d_in[14];
    const float* b2     = (const float*)d_in[15];
    const float* W3     = (const float*)d_in[16];
    const float* b3     = (const float*)d_in[17];

    // ws: wbuf[WBUF_WORDS] f32 | zmap[NPIX*32] f16
    size_t need = (size_t)WBUF_WORDS * sizeof(float)
                + (size_t)NPIX * 32 * sizeof(_Float16);
    if (ws_size < need) return;
    float* wbuf = (float*)d_ws;
    _Float16* zmap = (_Float16*)(wbuf + WBUF_WORDS);

    hipLaunchKernelGGL(prep1, dim3(21), dim3(256), 0, stream,
                       W_flow, b_flow, W_pc, b_pc, W1, b1, wbuf);
    hipLaunchKernelGGL(prep2, dim3(1), dim3(1024), 0, stream, wbuf, wbuf, W2);
    hipLaunchKernelGGL(conv_map, dim3(NPIX / 64), dim3(256), 0, stream,
                       pc0_map, flow_map, wbuf, zmap);
    hipLaunchKernelGGL(point_mlp, dim3(NPTS / 128), dim3(512), 0, stream,
                       zmap, pc0_fea, flows, pose_flows, radar_pose,
                       pidx, voxel, wbuf, b2, W3, b3, (float*)d_out);
}

// Round 15
// 186.041 us; speedup vs baseline: 1.9412x; 1.0442x over previous
//
#include <hip/hip_runtime.h>

#define NB 4
#define NN 200000
#define HH 512
#define WW 512
#define CC 64
#define PP 150000
#define RP 100000
#define HWSZ (HH * WW)                     // 262144 = 2^18
#define NPTS (NB * NN)
#define NPIX (NB * HWSZ)                   // 1048576
#define PIXB 256                           // pixels per conv block
#define ROWDW 256                          // pts32 row length in dwords (1KB)

// wbuf layout (32-bit words):
#define WB_WCAT 0
#define WB_WTAIL 5120
#define WB_BCAT 5312
#define WB_BFRAG 5376
#define WB_BFRAG2 (WB_BFRAG + 3072)
#define WBUF_WORDS (WB_BFRAG2 + 256)       // 8704

typedef _Float16 half8_t __attribute__((ext_vector_type(8)));
typedef _Float16 half2_t __attribute__((ext_vector_type(2)));
typedef float f32x4 __attribute__((ext_vector_type(4)));

__device__ __forceinline__ unsigned packh(float a, float b) {
    half2_t h; h.x = (_Float16)a; h.y = (_Float16)b;
    unsigned u; __builtin_memcpy(&u, &h, 4); return u;
}
__device__ __forceinline__ float gelu(float v) {
    return 0.5f * v * (1.0f + erff(v * 0.70710678118654752f));
}

// ---------------- prep1: collapsed weights (grid 21) ----------------

__global__ __launch_bounds__(256) void prep1(
    const float* __restrict__ Wf, const float* __restrict__ bf,
    const float* __restrict__ Wp, const float* __restrict__ bp,
    const float* __restrict__ W1, const float* __restrict__ b1,
    float* __restrict__ wbuf)
{
    int g = blockIdx.x * 256 + threadIdx.x;

    if (g < 5120) {                               // Wcat
        int r = g >> 5, j = g & 31;
        float s = 0.f;
        if (r < 64) {
            for (int k = 0; k < 32; ++k) s += Wf[r * 32 + k] * W1[k * 32 + j];
        } else {
            int rr = r - 64;
            for (int k = 0; k < 32; ++k) s += Wp[rr * 32 + k] * W1[(32 + k) * 32 + j];
        }
        wbuf[WB_WCAT + g] = s;
    } else if (g < 5312) {                        // Wtail
        int idx = g - 5120;
        int r = idx >> 5, j = idx & 31;
        float s = 0.f;
        for (int k = 0; k < 32; ++k) s += Wf[(64 + r) * 32 + k] * W1[k * 32 + j];
        wbuf[WB_WTAIL + idx] = s;
    } else if (g < 5344) {                        // bcat
        int j = g - 5312;
        float s = b1[j];
        for (int k = 0; k < 32; ++k)
            s += bf[k] * W1[k * 32 + j] + bp[k] * W1[(32 + k) * 32 + j];
        wbuf[WB_BCAT + j] = s;
    }
}

// ---------------- prep2: B-fragment build (1 block 1024) ----------------

__device__ __forceinline__ float wrowf(const float* __restrict__ wbuf, int k, int col) {
    if (k < 160) return wbuf[WB_WCAT + k * 32 + col];
    if (k < 166) return wbuf[WB_WTAIL + (k - 160) * 32 + col];
    if (k == 166) return wbuf[WB_BCAT + col];
    return 0.f;
}

__global__ __launch_bounds__(1024) void prep2(
    const float* __restrict__ wbufc, float* __restrict__ wbuf,
    const float* __restrict__ W2)
{
    int t = threadIdx.x;
    unsigned* BF = (unsigned*)(wbuf + WB_BFRAG);
    for (int idx = t; idx < 3072 + 256; idx += 1024) {
        if (idx < 3072) {
            int w = idx & 3;
            int slot = idx >> 2;
            int l = slot & 63;
            int rest = slot >> 6;
            int tt = rest % 6, nt = rest / 6;
            int k = tt * 32 + (l >> 4) * 8 + w * 2;
            int col = nt * 16 + (l & 15);
            BF[idx] = packh(wrowf(wbufc, k, col), wrowf(wbufc, k + 1, col));
        } else {
            int i2 = idx - 3072;
            int w = i2 & 3, l = i2 >> 2;
            int k2 = (l >> 4) * 8 + w * 2, col = l & 15;
            BF[i2 + 3072] = packh(W2[k2 * 16 + col], W2[(k2 + 1) * 16 + col]);
        }
    }
}

// ---------------- dense 1x1 conv v2: dwordx4-staged, LDS-transposed --------
// Block 256 thr = 4 waves = 256 pixels. Per 32-ch slice: wave wv stages
// channels wv*8..+7 with float4 loads (1KB/wave-instr), XOR-swizzled
// channel-major LDS; A-fragments built from ds_read_b32. T14 prefetch:
// next slice's loads issued before current slice's LDS reads.

__global__ __launch_bounds__(256) void conv_map(
    const float* __restrict__ pc0_map, const float* __restrict__ flow_map,
    const float* __restrict__ wbuf, _Float16* __restrict__ zmap)
{
    __shared__ uint4 Bf[832];                       // 13312 B
    __shared__ __align__(16) float pts32[32 * ROWDW];  // 32768 B
    __shared__ __align__(16) _Float16 zl[4][16 * 48];  // 6144 B

    {
        const uint4* wsrc = (const uint4*)(wbuf + WB_BFRAG);
        for (int i = threadIdx.x; i < 832; i += 256) Bf[i] = wsrc[i];
    }

    int tid = threadIdx.x;
    int lane = tid & 63, wv = tid >> 6;
    int lo = lane & 15, hi = lane >> 4;
    size_t pixbase = (size_t)blockIdx.x * PIXB;     // never straddles batch
    int b = (int)(pixbase >> 18);                   // HWSZ = 2^18
    size_t inb = pixbase & (size_t)(HWSZ - 1);

    const float* fmb = flow_map + (size_t)b * CC * HWSZ + inb;
    const float* pmb = pc0_map  + (size_t)b * CC * HWSZ + inb;

    f32x4 ld[8];
    {   // prefetch slice 0 (flow ch 0..31; wave wv: ch wv*8..+7; px 4*lane..+3)
        const float* base = fmb + (size_t)(wv * 8) * HWSZ + 4 * lane;
        #pragma unroll
        for (int i = 0; i < 8; ++i)
            ld[i] = *(const f32x4*)(base + (size_t)i * HWSZ);
    }

    f32x4 acc0[4], acc1[4];
    #pragma unroll
    for (int r = 0; r < 4; ++r) {
        acc0[r] = (f32x4){0.f, 0.f, 0.f, 0.f};
        acc1[r] = (f32x4){0.f, 0.f, 0.f, 0.f};
    }

    for (int t = 0; t < 4; ++t) {
        __syncthreads();        // prev slice's reads done (and Bf ready at t=0)
        // stage regs -> LDS, channel-major + XOR swizzle ((ch>>3)<<5)
        #pragma unroll
        for (int i = 0; i < 8; ++i) {
            int ch = wv * 8 + i;
            unsigned addr = ((unsigned)(ch * ROWDW + 4 * lane)) * 4u;
            addr ^= ((unsigned)(ch >> 3) & 3u) << 5;
            *(f32x4*)((char*)pts32 + addr) = ld[i];
        }
        __syncthreads();
        // prefetch next slice (loads in flight across the MFMA phase)
        if (t < 3) {
            int tn = t + 1;
            const float* mb = (tn < 2) ? fmb : pmb;
            const float* base = mb + (size_t)((tn & 1) * 32 + wv * 8) * HWSZ + 4 * lane;
            #pragma unroll
            for (int i = 0; i < 8; ++i)
                ld[i] = *(const f32x4*)(base + (size_t)i * HWSZ);
        }
        // compute this slice for all 4 tiles of this wave
        half8_t B0, B1;
        __builtin_memcpy(&B0, &Bf[t * 64 + lane], 16);
        __builtin_memcpy(&B1, &Bf[(6 + t) * 64 + lane], 16);
        #pragma unroll
        for (int tt = 0; tt < 4; ++tt) {
            int px = wv * 64 + tt * 16 + lo;
            half8_t A;
            #pragma unroll
            for (int j = 0; j < 8; ++j) {
                int ch = hi * 8 + j;
                unsigned addr = ((unsigned)(ch * ROWDW + px)) * 4u;
                addr ^= ((unsigned)(ch >> 3) & 3u) << 5;
                A[j] = (_Float16)(*(const float*)((const char*)pts32 + addr));
            }
            acc0[tt] = __builtin_amdgcn_mfma_f32_16x16x32_f16(A, B0, acc0[tt], 0, 0, 0);
            acc1[tt] = __builtin_amdgcn_mfma_f32_16x16x32_f16(A, B1, acc1[tt], 0, 0, 0);
        }
    }

    // epilogue: per tile, bounce C-layout -> pixel-major, 16B coalesced write
    _Float16* zw = zl[wv];
    #pragma unroll
    for (int tt = 0; tt < 4; ++tt) {
        #pragma unroll
        for (int r = 0; r < 4; ++r) {
            zw[(hi * 4 + r) * 48 + lo]      = (_Float16)acc0[tt][r];
            zw[(hi * 4 + r) * 48 + 16 + lo] = (_Float16)acc1[tt][r];
        }
        size_t pg = pixbase + wv * 64 + tt * 16 + lo;
        uint4 ov;
        __builtin_memcpy(&ov, &zw[lo * 48 + hi * 8], 16);
        *(uint4*)&zmap[pg * 32 + hi * 8] = ov;
    }
}

// ---------------- point phase: z = z_map + fea.W + tail.W, MLP tail ----------

__global__ __launch_bounds__(512, 8) void point_mlp(
    const _Float16* __restrict__ zmap,
    const float* __restrict__ pc0_fea, const float* __restrict__ flows,
    const float* __restrict__ pose_flows, const float* __restrict__ radar_pose,
    const int* __restrict__ point_idxes, const int* __restrict__ voxel,
    const float* __restrict__ wbuf,
    const float* __restrict__ b2, const float* __restrict__ W3,
    const float* __restrict__ b3,
    float* __restrict__ out)
{
    __shared__ uint4 Bf[832];
    __shared__ __align__(16) _Float16 zl[8][16 * 48];
    {
        const uint4* wsrc = (const uint4*)(wbuf + WB_BFRAG);
        for (int i = threadIdx.x; i < 832; i += 512) Bf[i] = wsrc[i];
    }
    __syncthreads();

    int wv = threadIdx.x >> 6;
    int lane = threadIdx.x & 63;
    int lo = lane & 15, hi = lane >> 4;
    int pid0 = (blockIdx.x * 8 + wv) * 16;       // tiles never straddle batches
    int pid = pid0 + lo;
    int b = pid0 / NN;

    // A4: fea slice (coalesced streaming: consecutive pids)
    half8_t A4;
    {
        const f32x4* fe4 = (const f32x4*)(pc0_fea + (size_t)pid * 32 + hi * 8);
        f32x4 fa = fe4[0];
        f32x4 fb = fe4[1];
        A4[0] = (_Float16)fa.x; A4[1] = (_Float16)fa.y;
        A4[2] = (_Float16)fa.z; A4[3] = (_Float16)fa.w;
        A4[4] = (_Float16)fb.x; A4[5] = (_Float16)fb.y;
        A4[6] = (_Float16)fb.z; A4[7] = (_Float16)fb.w;
    }
    // A5: tail (flows3, pose3, bias-one)
    half8_t A5;
    {
        #pragma unroll
        for (int j = 0; j < 8; ++j) A5[j] = (_Float16)0.f;
        if (hi == 0) {
            const float* fl = flows + (size_t)pid * 3;
            int pi = point_idxes[pid];
            const float* ps = (pi < PP) ? (pose_flows + ((size_t)b * PP + pi) * 3)
                                        : (radar_pose + ((size_t)b * RP + (pi - PP)) * 3);
            A5[0] = (_Float16)fl[0]; A5[1] = (_Float16)fl[1]; A5[2] = (_Float16)fl[2];
            A5[3] = (_Float16)ps[0]; A5[4] = (_Float16)ps[1]; A5[5] = (_Float16)ps[2];
            A5[6] = (_Float16)1.0f;
        }
    }
    // A6: z_map row (64B per point, L3-resident)
    half8_t A6;
    {
        int y = voxel[(size_t)pid * 3 + 1];
        int x = voxel[(size_t)pid * 3 + 2];
        size_t pix = ((size_t)b << 18) + (size_t)y * WW + x;
        uint4 zr = *(const uint4*)&zmap[pix * 32 + hi * 8];
        __builtin_memcpy(&A6, &zr, 16);
    }
    // identity B-fragments for the z_map addend (exact in f16)
    half8_t B60, B61;
    {
        unsigned w0[4], w1[4];
        #pragma unroll
        for (int w = 0; w < 4; ++w) {
            int k0 = hi * 8 + 2 * w, k1 = k0 + 1;
            unsigned a = 0, bmask = 0;
            if (k0 == lo) a |= 0x3C00u;
            if (k1 == lo) a |= 0x3C000000u;
            if (k0 == lo + 16) bmask |= 0x3C00u;
            if (k1 == lo + 16) bmask |= 0x3C000000u;
            w0[w] = a; w1[w] = bmask;
        }
        __builtin_memcpy(&B60, w0, 16);
        __builtin_memcpy(&B61, w1, 16);
    }

    f32x4 acc0 = {0.f, 0.f, 0.f, 0.f};
    f32x4 acc1 = {0.f, 0.f, 0.f, 0.f};
    acc0 = __builtin_amdgcn_mfma_f32_16x16x32_f16(A6, B60, acc0, 0, 0, 0);
    acc1 = __builtin_amdgcn_mfma_f32_16x16x32_f16(A6, B61, acc1, 0, 0, 0);
    {
        half8_t B0, B1;
        uint4 u0 = Bf[4 * 64 + lane];
        uint4 u1 = Bf[(6 + 4) * 64 + lane];
        __builtin_memcpy(&B0, &u0, 16);
        __builtin_memcpy(&B1, &u1, 16);
        acc0 = __builtin_amdgcn_mfma_f32_16x16x32_f16(A4, B0, acc0, 0, 0, 0);
        acc1 = __builtin_amdgcn_mfma_f32_16x16x32_f16(A4, B1, acc1, 0, 0, 0);
        uint4 u2 = Bf[5 * 64 + lane];
        uint4 u3 = Bf[(6 + 5) * 64 + lane];
        __builtin_memcpy(&B0, &u2, 16);
        __builtin_memcpy(&B1, &u3, 16);
        acc0 = __builtin_amdgcn_mfma_f32_16x16x32_f16(A5, B0, acc0, 0, 0, 0);
        acc1 = __builtin_amdgcn_mfma_f32_16x16x32_f16(A5, B1, acc1, 0, 0, 0);
    }

    // gelu -> z LDS (f16)
    _Float16* zw = zl[wv];
    #pragma unroll
    for (int r = 0; r < 4; ++r) {
        zw[(hi * 4 + r) * 48 + lo]      = (_Float16)gelu(acc0[r]);
        zw[(hi * 4 + r) * 48 + 16 + lo] = (_Float16)gelu(acc1[r]);
    }

    // layer2
    half8_t A2, B2;
    __builtin_memcpy(&A2, &zw[lo * 48 + hi * 8], 16);
    {
        uint4 u2 = Bf[768 + lane];
        __builtin_memcpy(&B2, &u2, 16);
    }
    f32x4 zz4 = {0.f, 0.f, 0.f, 0.f};
    f32x4 acc2 = __builtin_amdgcn_mfma_f32_16x16x32_f16(A2, B2, zz4, 0, 0, 0);

    // epilogue
    float b2v = b2[lo];
    float w3v = W3[lo];
    float e0 = gelu(acc2[0] + b2v) * w3v;
    float e1 = gelu(acc2[1] + b2v) * w3v;
    float e2 = gelu(acc2[2] + b2v) * w3v;
    float e3 = gelu(acc2[3] + b2v) * w3v;
    #pragma unroll
    for (int m = 1; m <= 8; m <<= 1) {
        e0 += __shfl_xor(e0, m);
        e1 += __shfl_xor(e1, m);
        e2 += __shfl_xor(e2, m);
        e3 += __shfl_xor(e3, m);
    }
    int p2 = hi * 4 + lo;
    if (lo < 4) {
        float zs = (lo == 0 ? e0 : lo == 1 ? e1 : lo == 2 ? e2 : e3) + b3[0];
        float score = 1.0f / (1.0f + expf(-zs));
        int pid2 = pid0 + p2;
        out[(size_t)NPTS + pid2] = score;
        out[pid2] = (score > 0.5f) ? 1.0f : 0.0f;
    }
}

extern "C" void kernel_launch(void* const* d_in, const int* in_sizes, int n_in,
                              void* d_out, int out_size, void* d_ws, size_t ws_size,
                              hipStream_t stream) {
    const float* pc0_map    = (const float*)d_in[0];
    const float* flow_map   = (const float*)d_in[1];
    const float* pc0_fea    = (const float*)d_in[2];
    const float* flows      = (const float*)d_in[3];
    const float* pose_flows = (const float*)d_in[4];
    const float* radar_pose = (const float*)d_in[5];
    const int*   voxel      = (const int*)d_in[6];
    const int*   pidx       = (const int*)d_in[7];
    const float* W_flow = (const float*)d_in[8];
    const float* b_flow = (const float*)d_in[9];
    const float* W_pc   = (const float*)d_in[10];
    const float* b_pc   = (const float*)d_in[11];
    const float* W1     = (const float*)d_in[12];
    const float* b1     = (const float*)d_in[13];
    const float* W2     = (const float*)d_in[14];
    const float* b2     = (const float*)d_in[15];
    const float* W3     = (const float*)d_in[16];
    const float* b3     = (const float*)d_in[17];

    // ws: wbuf[WBUF_WORDS] f32 | zmap[NPIX*32] f16
    size_t need = (size_t)WBUF_WORDS * sizeof(float)
                + (size_t)NPIX * 32 * sizeof(_Float16);
    if (ws_size < need) return;
    float* wbuf = (float*)d_ws;
    _Float16* zmap = (_Float16*)(wbuf + WBUF_WORDS);

    hipLaunchKernelGGL(prep1, dim3(21), dim3(256), 0, stream,
                       W_flow, b_flow, W_pc, b_pc, W1, b1, wbuf);
    hipLaunchKernelGGL(prep2, dim3(1), dim3(1024), 0, stream, wbuf, wbuf, W2);
    hipLaunchKernelGGL(conv_map, dim3(NPIX / PIXB), dim3(256), 0, stream,
                       pc0_map, flow_map, wbuf, zmap);
    hipLaunchKernelGGL(point_mlp, dim3(NPTS / 128), dim3(512), 0, stream,
                       zmap, pc0_fea, flows, pose_flows, radar_pose,
                       pidx, voxel, wbuf, b2, W3, b3, (float*)d_out);
}